// Round 9
// baseline (128.900 us; speedup 1.0000x reference)
//
#include <hip/hip_runtime.h>

typedef __attribute__((ext_vector_type(8))) short short8;   // 8 x bf16
typedef __attribute__((ext_vector_type(4))) float f32x4;
typedef __attribute__((ext_vector_type(4))) unsigned int uint4v;

#define B_SZ 256
#define T_SZ 2048
#define D_SZ 64
#define TILES_PER_WAVE 4   // 16 rows each -> 64 rows per wave
#define SEGS 8             // blocks per b; 4 waves * 64 rows * 8 = 2048 rows
#define APAD 68            // a_lds row stride in dwords (68%32=4 -> 2-way writes)
#define P_OFF_BYTES (1u << 20)
#define P_BYTES ((size_t)B_SZ * T_SZ * D_SZ * 2)

#define KEEP(v) asm volatile("" : "+v"(v))

// round-half-up to bf16, returned as fp32 bit pattern with low 16 bits zero
__device__ __forceinline__ unsigned int bf16_hi_bits(float f) {
    return (__float_as_uint(f) + 0x8000u) & 0xffff0000u;
}
// pack two positive floats to 2 bf16 in one dword (round-half-up)
__device__ __forceinline__ unsigned int pack_bf16(float a, float b) {
    return ((__float_as_uint(a) + 0x8000u) >> 16) |
           ((__float_as_uint(b) + 0x8000u) & 0xffff0000u);
}

// Split 8 fp32 into hi + lo bf16x8 MFMA A-fragments: x = hi + lo
__device__ __forceinline__ void split8(const float4 a, const float4 b,
                                       short8& hi, short8& lo) {
    const float v[8] = {a.x, a.y, a.z, a.w, b.x, b.y, b.z, b.w};
    unsigned int h[4], l[4];
#pragma unroll
    for (int i = 0; i < 8; i += 2) {
        const unsigned int h0 = bf16_hi_bits(v[i]);
        const unsigned int h1 = bf16_hi_bits(v[i + 1]);
        h[i >> 1] = (h0 >> 16) | (h1 & 0xffff0000u);
        const float l0 = v[i] - __uint_as_float(h0);
        const float l1 = v[i + 1] - __uint_as_float(h1);
        l[i >> 1] = ((__float_as_uint(l0) + 0x8000u) >> 16) |
                    ((__float_as_uint(l1) + 0x8000u) & 0xffff0000u);
    }
    const uint4v hu = {h[0], h[1], h[2], h[3]};
    const uint4v lu = {l[0], l[1], l[2], l[3]};
    hi = __builtin_bit_cast(short8, hu);
    lo = __builtin_bit_cast(short8, lu);
}

// exp(tanh(e)) via tanh = 1 - 2/(1+exp(2e))
__device__ __forceinline__ float exp_tanh(float e) {
    const float u = __expf(2.0f * e);
    const float rr = __builtin_amdgcn_rcpf(1.0f + u);
    return __expf(1.0f - 2.0f * rr);
}

// Grid of 16 blocks: every block zeroes its 4 KB slice of S; block 0 also
// builds W fragments in MFMA B-operand order. Frag f = ((nb*2+kb)*2+h):
// lane l holds B[k = kb*32 + (l>>4)*8 + i][n = nb*16 + (l&15)], i=0..7.
__global__ __launch_bounds__(256) void tca_prep(const float* __restrict__ W,
                                                unsigned int* __restrict__ Wf,
                                                float* __restrict__ S) {
    const int tid = threadIdx.x;
    const float4 z = make_float4(0.f, 0.f, 0.f, 0.f);
    ((float4*)S)[blockIdx.x * 256 + tid] = z;   // 16 blocks * 4 KB = 64 KB

    if (blockIdx.x != 0) return;
#pragma unroll
    for (int u = 0; u < 4; ++u) {
        const int lf = tid + u * 256;   // 0..1023
        const int f = lf >> 6;
        const int lane = lf & 63;
        const int nb = f >> 2;
        const int kb = (f >> 1) & 1;
        const int h = f & 1;
        const int col = nb * 16 + (lane & 15);
        const int krow = kb * 32 + (lane >> 4) * 8;
        unsigned int d[4];
#pragma unroll
        for (int i = 0; i < 8; i += 2) {
            const float w0 = W[(krow + i) * D_SZ + col];
            const float w1 = W[(krow + i + 1) * D_SZ + col];
            unsigned int b0, b1;
            if (h == 0) {
                b0 = bf16_hi_bits(w0);
                b1 = bf16_hi_bits(w1);
            } else {
                const float l0 = w0 - __uint_as_float(bf16_hi_bits(w0));
                const float l1 = w1 - __uint_as_float(bf16_hi_bits(w1));
                b0 = (__float_as_uint(l0) + 0x8000u) & 0xffff0000u;
                b1 = (__float_as_uint(l1) + 0x8000u) & 0xffff0000u;
            }
            d[i >> 1] = (b0 >> 16) | (b1 & 0xffff0000u);
        }
        const uint4v dv = {d[0], d[1], d[2], d[3]};
        ((uint4v*)Wf)[f * 64 + lane] = dv;
    }
}

// 3-term split matmul; p = exp(tanh(x@W + bias)); column-sums into S.
// STORE_P: additionally store p (bf16, row-major) to p_ws via LDS transpose.
template <bool STORE_P>
__global__ __launch_bounds__(256, 2) void tca_pass0(
        const float* __restrict__ x, const unsigned int* __restrict__ Wf,
        const float* __restrict__ bias, float* __restrict__ S,
        unsigned short* __restrict__ p_ws) {
    __shared__ float a_lds[4][16 * APAD];   // per-wave transpose slab

    const int wave = threadIdx.x >> 6;
    const int lane = threadIdx.x & 63;
    const int b = blockIdx.x >> 3;
    const int seg = blockIdx.x & (SEGS - 1);

    const int arow = lane & 15;          // A row within 16-row tile
    const int aoff = (lane >> 4) * 8;    // A k-base within 32-block
    const int crow = (lane >> 4) * 4;    // C row base
    const int ccol = lane & 15;          // C col within 16-block

    // W fragments -> registers, pinned with empty-asm keeps.
    short8 wh[4][2], wl[4][2];
#pragma unroll
    for (int nb = 0; nb < 4; ++nb)
#pragma unroll
        for (int kb = 0; kb < 2; ++kb) {
            const int fb = (nb * 2 + kb) * 2;
            wh[nb][kb] = __builtin_bit_cast(short8, ((const uint4v*)Wf)[fb * 64 + lane]);
            KEEP(wh[nb][kb]);
            wl[nb][kb] = __builtin_bit_cast(short8, ((const uint4v*)Wf)[(fb + 1) * 64 + lane]);
            KEEP(wl[nb][kb]);
        }

    float csum[4] = {0.f, 0.f, 0.f, 0.f};

    const int t_wave = seg * 256 + wave * 64;
    for (int tile = 0; tile < TILES_PER_WAVE; ++tile) {
        const int t0 = t_wave + tile * 16;
        const float* xrow = x + ((size_t)b * T_SZ + t0 + arow) * D_SZ + aoff;
        const float4 xa0 = *(const float4*)(xrow);
        const float4 xa1 = *(const float4*)(xrow + 4);
        const float4 xb0 = *(const float4*)(xrow + 32);
        const float4 xb1 = *(const float4*)(xrow + 36);

        short8 ah[2], al[2];
        split8(xa0, xa1, ah[0], al[0]);
        split8(xb0, xb1, ah[1], al[1]);

        f32x4 c[4];
#pragma unroll
        for (int nb = 0; nb < 4; ++nb) {
            f32x4 acc = {0.f, 0.f, 0.f, 0.f};
#pragma unroll
            for (int kb = 0; kb < 2; ++kb) {
                acc = __builtin_amdgcn_mfma_f32_16x16x32_bf16(ah[kb], wh[nb][kb], acc, 0, 0, 0);
                acc = __builtin_amdgcn_mfma_f32_16x16x32_bf16(ah[kb], wl[nb][kb], acc, 0, 0, 0);
                acc = __builtin_amdgcn_mfma_f32_16x16x32_bf16(al[kb], wh[nb][kb], acc, 0, 0, 0);
            }
            c[nb] = acc;
        }

        // Epilogue at C-layout; bias via L2-hot scattered dwords off one base.
        const float* brow = bias + (size_t)(t0 + crow) * D_SZ + ccol;
#pragma unroll
        for (int nb = 0; nb < 4; ++nb) {
#pragma unroll
            for (int r = 0; r < 4; ++r) {
                const float p = exp_tanh(c[nb][r] + brow[r * D_SZ + nb * 16]);
                csum[nb] += p;
                if (STORE_P)
                    a_lds[wave][(crow + r) * APAD + nb * 16 + ccol] = p;
            }
        }

        if (STORE_P) {
            // Transpose-read at A-layout, pack to bf16, store coalesced 16B x2.
            const float* as = &a_lds[wave][arow * APAD + aoff];
            const float4 p0 = *(const float4*)(as);
            const float4 p1 = *(const float4*)(as + 4);
            const float4 p2 = *(const float4*)(as + 32);
            const float4 p3 = *(const float4*)(as + 36);
            unsigned short* dst = p_ws + ((size_t)b * T_SZ + t0 + arow) * D_SZ + aoff;
            const uint4v q0 = {pack_bf16(p0.x, p0.y), pack_bf16(p0.z, p0.w),
                               pack_bf16(p1.x, p1.y), pack_bf16(p1.z, p1.w)};
            const uint4v q1 = {pack_bf16(p2.x, p2.y), pack_bf16(p2.z, p2.w),
                               pack_bf16(p3.x, p3.y), pack_bf16(p3.z, p3.w)};
            *(uint4v*)(dst) = q0;
            *(uint4v*)(dst + 32) = q1;
        }
    }

#pragma unroll
    for (int nb = 0; nb < 4; ++nb) {
        float v = csum[nb];
        v += __shfl_xor(v, 16, 64);
        v += __shfl_xor(v, 32, 64);
        if (lane < 16) atomicAdd(&S[b * D_SZ + nb * 16 + lane], v);
    }
}

// Streaming pass: out = x * bf16(p) * rcp(S).  256 rows of one b per block.
__global__ __launch_bounds__(256, 8) void tca_scale(
        const float* __restrict__ x, const unsigned short* __restrict__ p_ws,
        const float* __restrict__ S, float* __restrict__ out) {
    const int tid = threadIdx.x;
    const int b = blockIdx.x >> 3;
    const int seg = blockIdx.x & 7;
    const int dblk = tid & 7;        // 8 d-columns per thread
    const int rr = tid >> 3;         // 32 rows per sweep

    const float4 s0 = *(const float4*)(S + b * D_SZ + dblk * 8);
    const float4 s1 = *(const float4*)(S + b * D_SZ + dblk * 8 + 4);
    const float r0 = __builtin_amdgcn_rcpf(s0.x), r1 = __builtin_amdgcn_rcpf(s0.y);
    const float r2 = __builtin_amdgcn_rcpf(s0.z), r3 = __builtin_amdgcn_rcpf(s0.w);
    const float r4 = __builtin_amdgcn_rcpf(s1.x), r5 = __builtin_amdgcn_rcpf(s1.y);
    const float r6 = __builtin_amdgcn_rcpf(s1.z), r7 = __builtin_amdgcn_rcpf(s1.w);

#pragma unroll
    for (int sweep = 0; sweep < 8; ++sweep) {
        const int t = seg * 256 + sweep * 32 + rr;
        const size_t base = ((size_t)b * T_SZ + t) * D_SZ + dblk * 8;
        const float4 x0 = *(const float4*)(x + base);
        const float4 x1 = *(const float4*)(x + base + 4);
        const uint4v pv = *(const uint4v*)(p_ws + base);
        float4 o0, o1;
        o0.x = x0.x * __uint_as_float(pv.x << 16) * r0;
        o0.y = x0.y * __uint_as_float(pv.x & 0xffff0000u) * r1;
        o0.z = x0.z * __uint_as_float(pv.y << 16) * r2;
        o0.w = x0.w * __uint_as_float(pv.y & 0xffff0000u) * r3;
        o1.x = x1.x * __uint_as_float(pv.z << 16) * r4;
        o1.y = x1.y * __uint_as_float(pv.z & 0xffff0000u) * r5;
        o1.z = x1.z * __uint_as_float(pv.w << 16) * r6;
        o1.w = x1.w * __uint_as_float(pv.w & 0xffff0000u) * r7;
        *(float4*)(out + base) = o0;
        *(float4*)(out + base + 4) = o1;
    }
}

// Fallback (ws too small): recompute matmul in pass 1 (round-8 structure).
__global__ __launch_bounds__(256, 2) void tca_out_recompute(
        const float* __restrict__ x, const unsigned int* __restrict__ Wf,
        const float* __restrict__ bias, float* __restrict__ S,
        float* __restrict__ out) {
    __shared__ float a_lds[4][16 * APAD];
    const int wave = threadIdx.x >> 6;
    const int lane = threadIdx.x & 63;
    const int b = blockIdx.x >> 3;
    const int seg = blockIdx.x & (SEGS - 1);
    const int arow = lane & 15, aoff = (lane >> 4) * 8;
    const int crow = (lane >> 4) * 4, ccol = lane & 15;

    short8 wh[4][2], wl[4][2];
#pragma unroll
    for (int nb = 0; nb < 4; ++nb)
#pragma unroll
        for (int kb = 0; kb < 2; ++kb) {
            const int fb = (nb * 2 + kb) * 2;
            wh[nb][kb] = __builtin_bit_cast(short8, ((const uint4v*)Wf)[fb * 64 + lane]);
            KEEP(wh[nb][kb]);
            wl[nb][kb] = __builtin_bit_cast(short8, ((const uint4v*)Wf)[(fb + 1) * 64 + lane]);
            KEEP(wl[nb][kb]);
        }
    float rcpS[4];
#pragma unroll
    for (int nb = 0; nb < 4; ++nb)
        rcpS[nb] = __builtin_amdgcn_rcpf(S[b * D_SZ + nb * 16 + ccol]);

    const int t_wave = seg * 256 + wave * 64;
    for (int tile = 0; tile < TILES_PER_WAVE; ++tile) {
        const int t0 = t_wave + tile * 16;
        const float* xrow = x + ((size_t)b * T_SZ + t0 + arow) * D_SZ + aoff;
        const float4 xa0 = *(const float4*)(xrow);
        const float4 xa1 = *(const float4*)(xrow + 4);
        const float4 xb0 = *(const float4*)(xrow + 32);
        const float4 xb1 = *(const float4*)(xrow + 36);
        short8 ah[2], al[2];
        split8(xa0, xa1, ah[0], al[0]);
        split8(xb0, xb1, ah[1], al[1]);
        f32x4 c[4];
#pragma unroll
        for (int nb = 0; nb < 4; ++nb) {
            f32x4 acc = {0.f, 0.f, 0.f, 0.f};
#pragma unroll
            for (int kb = 0; kb < 2; ++kb) {
                acc = __builtin_amdgcn_mfma_f32_16x16x32_bf16(ah[kb], wh[nb][kb], acc, 0, 0, 0);
                acc = __builtin_amdgcn_mfma_f32_16x16x32_bf16(ah[kb], wl[nb][kb], acc, 0, 0, 0);
                acc = __builtin_amdgcn_mfma_f32_16x16x32_bf16(al[kb], wh[nb][kb], acc, 0, 0, 0);
            }
            c[nb] = acc;
        }
        const float* brow = bias + (size_t)(t0 + crow) * D_SZ + ccol;
#pragma unroll
        for (int nb = 0; nb < 4; ++nb)
#pragma unroll
            for (int r = 0; r < 4; ++r)
                a_lds[wave][(crow + r) * APAD + nb * 16 + ccol] =
                    exp_tanh(c[nb][r] + brow[r * D_SZ + nb * 16]) * rcpS[nb];

        const float* as = &a_lds[wave][arow * APAD + aoff];
        const float4 a0 = *(const float4*)(as);
        const float4 a1 = *(const float4*)(as + 4);
        const float4 a2 = *(const float4*)(as + 32);
        const float4 a3 = *(const float4*)(as + 36);
        float* orow = out + ((size_t)b * T_SZ + t0 + arow) * D_SZ + aoff;
        float4 o;
        o.x = xa0.x * a0.x; o.y = xa0.y * a0.y; o.z = xa0.z * a0.z; o.w = xa0.w * a0.w;
        *(float4*)(orow) = o;
        o.x = xa1.x * a1.x; o.y = xa1.y * a1.y; o.z = xa1.z * a1.z; o.w = xa1.w * a1.w;
        *(float4*)(orow + 4) = o;
        o.x = xb0.x * a2.x; o.y = xb0.y * a2.y; o.z = xb0.z * a2.z; o.w = xb0.w * a2.w;
        *(float4*)(orow + 32) = o;
        o.x = xb1.x * a3.x; o.y = xb1.y * a3.y; o.z = xb1.z * a3.z; o.w = xb1.w * a3.w;
        *(float4*)(orow + 36) = o;
    }
}

extern "C" void kernel_launch(void* const* d_in, const int* in_sizes, int n_in,
                              void* d_out, int out_size, void* d_ws, size_t ws_size,
                              hipStream_t stream) {
    const float* x = (const float*)d_in[0];
    const float* W = (const float*)d_in[1];
    const float* bias = (const float*)d_in[2];
    float* out = (float*)d_out;

    unsigned int* Wf = (unsigned int*)d_ws;   // 16 KB of W fragments
    float* S = (float*)d_ws + 4096;           // B*D floats = 64 KB
    unsigned short* p_ws = (unsigned short*)((char*)d_ws + P_OFF_BYTES);
    const bool use_p = ws_size >= (size_t)P_OFF_BYTES + P_BYTES;

    tca_prep<<<16, 256, 0, stream>>>(W, Wf, S);   // zeroes S + builds Wf

    const dim3 grid(B_SZ * SEGS);   // 2048 blocks, 4 waves each
    const dim3 block(256);
    if (use_p) {
        tca_pass0<true><<<grid, block, 0, stream>>>(x, Wf, bias, S, p_ws);
        tca_scale<<<grid, block, 0, stream>>>(x, p_ws, S, out);
    } else {
        tca_pass0<false><<<grid, block, 0, stream>>>(x, Wf, bias, S, p_ws);
        tca_out_recompute<<<grid, block, 0, stream>>>(x, Wf, bias, S, out);
    }
}